// Round 1
// baseline (528.297 us; speedup 1.0000x reference)
//
#include <hip/hip_runtime.h>

#define NB    2
#define CIN   64
#define COUT  64
#define KS    9
#define NLAT  181
#define NLON  360
#define NPER  24
#define TP    192     // p per workgroup
#define PRANGE 48     // p per wave
#define NPT   3       // 16-wide p-tiles per wave

typedef _Float16 f16;
typedef _Float16 f16x8 __attribute__((ext_vector_type(8)));
typedef _Float16 f16x4 __attribute__((ext_vector_type(4)));
typedef float    f32x4 __attribute__((ext_vector_type(4)));

// LDS carve: xs = 3*360*64 f16 (138240 B, swizzled [slot][lon][c]),
//            bounce = 16*376 f16 (12032 B)  -> total 150272 B
#define XS_ELEMS   (3 * NLON * CIN)
#define BOUNCE_ROW 376
#define LDS_BYTES  (XS_ELEMS * 2 + 16 * BOUNCE_ROW * 2)

__global__ __launch_bounds__(256, 1)
void disco_conv_kernel(const float* __restrict__ x,
                       const float* __restrict__ psi_vals,
                       const float* __restrict__ weight,
                       const float* __restrict__ bias,
                       const int* __restrict__ psi_lat_in,
                       const int* __restrict__ psi_lon_in,
                       float* __restrict__ out)
{
    extern __shared__ f16 smem[];
    f16* xs     = smem;              // [slot][lon][c-swizzled]
    f16* bounce = smem + XS_ELEMS;   // [16][BOUNCE_ROW]

    const int tid  = threadIdx.x;
    const int lane = tid & 63;
    const int wave = tid >> 6;
    const int pn   = lane & 15;      // MFMA n / m index
    const int q    = lane >> 4;      // MFMA k-group

    const int pchunk = blockIdx.x;   // 0..1
    const int lat    = blockIdx.y;   // 0..180
    const int b      = blockIdx.z;   // 0..1
    const int pw     = pchunk * TP + wave * PRANGE;

    // ---------------- stage x rows: f32 [c][lon] -> f16 swizzled [lon][c] ----
    for (int s = 0; s < 3; ++s) {
        int row = lat - 1 + s;
        row = row < 0 ? 0 : (row > NLAT - 1 ? NLAT - 1 : row);
        const float* xbase = x + ((size_t)b * CIN * NLAT + row) * NLON;
        for (int cq = 0; cq < 4; ++cq) {
            // hop1: coalesced global float4 -> bounce [cl][lon]
            for (int i = tid; i < 16 * 90; i += 256) {
                int cl = i / 90;
                int l4 = (i - cl * 90) * 4;
                const float* src = xbase + (size_t)(cq * 16 + cl) * (NLAT * NLON) + l4;
                float4 v = *(const float4*)src;
                f16x4 h;
                h[0] = (f16)v.x; h[1] = (f16)v.y; h[2] = (f16)v.z; h[3] = (f16)v.w;
                *(f16x4*)&bounce[cl * BOUNCE_ROW + l4] = h;
            }
            __syncthreads();
            // hop2: transpose into xs with oct ^ (lon&7) swizzle
            {
                int cl = tid & 15;
                int cg = cq * 16 + cl;
                int o8 = cg >> 3, ci = cg & 7;
                for (int o = tid >> 4; o < 45; o += 16) {
                    f16x8 vv = *(const f16x8*)&bounce[cl * BOUNCE_ROW + o * 8];
#pragma unroll
                    for (int i2 = 0; i2 < 8; ++i2) {
                        int lon = o * 8 + i2;          // lon & 7 == i2
                        xs[(s * NLON + lon) * CIN + (((o8 ^ i2) << 3) + ci)] = vv[i2];
                    }
                }
            }
            __syncthreads();
        }
    }

    // per-lane p values, pre-wrapped into [0,360)
    int pl[NPT];
#pragma unroll
    for (int pt = 0; pt < NPT; ++pt) {
        int p = pw + pt * 16 + pn;
        pl[pt] = p >= NLON ? p - NLON : p;
    }

    f32x4 D[4][NPT];
#pragma unroll
    for (int ft = 0; ft < 4; ++ft)
#pragma unroll
        for (int pt = 0; pt < NPT; ++pt)
            D[ft][pt] = (f32x4){0.f, 0.f, 0.f, 0.f};

    for (int k = 0; k < KS; ++k) {
        float acc[2][NPT][8];
#pragma unroll
        for (int cc = 0; cc < 2; ++cc)
#pragma unroll
            for (int pt = 0; pt < NPT; ++pt)
#pragma unroll
                for (int i2 = 0; i2 < 8; ++i2) acc[cc][pt][i2] = 0.f;

        const int e0 = (k * NLAT + lat) * NPER;
#pragma unroll 4
        for (int t = 0; t < NPER; ++t) {
            const float pv = psi_vals[e0 + t];      // wave-uniform -> s_load
            const int   li = psi_lat_in[e0 + t];
            const int   lo = psi_lon_in[e0 + t];
            const int slot = li - lat + 1;          // 0..2 (metadata pre-clipped)
            const int rowb = slot * NLON;
#pragma unroll
            for (int pt = 0; pt < NPT; ++pt) {
                int idx = lo + pl[pt];
                idx = idx >= NLON ? idx - NLON : idx;
                const f16* base = &xs[(rowb + idx) * CIN];
                const int sw = idx & 7;
                f16x8 xv0 = *(const f16x8*)(base + (((q    ) ^ sw) << 3));
                f16x8 xv1 = *(const f16x8*)(base + (((4 + q) ^ sw) << 3));
#pragma unroll
                for (int i2 = 0; i2 < 8; ++i2) {
                    acc[0][pt][i2] += pv * (float)xv0[i2];
                    acc[1][pt][i2] += pv * (float)xv1[i2];
                }
            }
        }

        // B fragments: B[k=c][n=p], lane: n = pn, k = q*8+j (+32*cc)
        f16x8 Bf[2][NPT];
#pragma unroll
        for (int cc = 0; cc < 2; ++cc)
#pragma unroll
            for (int pt = 0; pt < NPT; ++pt)
#pragma unroll
                for (int i2 = 0; i2 < 8; ++i2)
                    Bf[cc][pt][i2] = (f16)acc[cc][pt][i2];

        // A fragments: A[m=f][k=c], lane: m = pn, k = q*8+j (+32*cc)
        f16x8 Af[4][2];
#pragma unroll
        for (int ft = 0; ft < 4; ++ft)
#pragma unroll
            for (int cc = 0; cc < 2; ++cc) {
                const int f  = ft * 16 + pn;
                const int cb = cc * 32 + q * 8;
#pragma unroll
                for (int j = 0; j < 8; ++j)
                    Af[ft][cc][j] = (f16)weight[((size_t)f * CIN + cb + j) * KS + k];
            }

#pragma unroll
        for (int ft = 0; ft < 4; ++ft)
#pragma unroll
            for (int pt = 0; pt < NPT; ++pt)
#pragma unroll
                for (int cc = 0; cc < 2; ++cc)
                    D[ft][pt] = __builtin_amdgcn_mfma_f32_16x16x32_f16(
                        Af[ft][cc], Bf[cc][pt], D[ft][pt], 0, 0, 0);
    }

    // epilogue: D[m=f][n=p], lane holds col=pn, rows (lane>>4)*4+r
#pragma unroll
    for (int ft = 0; ft < 4; ++ft) {
#pragma unroll
        for (int pt = 0; pt < NPT; ++pt) {
            const int p = pw + pt * 16 + pn;
            if (p < NLON) {
#pragma unroll
                for (int r = 0; r < 4; ++r) {
                    const int f = ft * 16 + q * 4 + r;
                    out[((size_t)(b * COUT + f) * NLAT + lat) * NLON + p] =
                        D[ft][pt][r] + bias[f];
                }
            }
        }
    }
}

extern "C" void kernel_launch(void* const* d_in, const int* in_sizes, int n_in,
                              void* d_out, int out_size, void* d_ws, size_t ws_size,
                              hipStream_t stream) {
    const float* x          = (const float*)d_in[0];
    const float* psi_vals   = (const float*)d_in[1];
    const float* weight     = (const float*)d_in[2];
    const float* bias       = (const float*)d_in[3];
    // d_in[4] = psi_ker, d_in[5] = psi_lat_out: implied by structured layout
    const int*   psi_lat_in = (const int*)d_in[6];
    const int*   psi_lon_in = (const int*)d_in[7];
    float* out = (float*)d_out;

    static bool attr_set = false;   // idempotent; same work every call
    (void)hipFuncSetAttribute((const void*)disco_conv_kernel,
                              hipFuncAttributeMaxDynamicSharedMemorySize, LDS_BYTES);

    dim3 grid(2, NLAT, NB);
    disco_conv_kernel<<<grid, 256, LDS_BYTES, stream>>>(
        x, psi_vals, weight, bias, psi_lat_in, psi_lon_in, out);
}

// Round 2
// 291.653 us; speedup vs baseline: 1.8114x; 1.8114x over previous
//
#include <hip/hip_runtime.h>

// DISCO S2 conv, round 2.
// Strategy: prep kernel transposes x -> xT f16 [b][h(c/32)][lat][lon][32c, oct^((lon>>1)&3) swizzled]
// and weight -> wT f16 [k][f][c]. Main kernel: per (pchunk,lat,b), loop c-halves:
// linear-copy 3 swizzled rows into 69KB LDS (2 wg/CU), gather taps with pk_fma f16
// accumulate directly into MFMA B-fragments, 16x16x32_f16 MFMA, fused bias+store.

#define NB    2
#define CIN   64
#define COUT  64
#define KS    9
#define NLAT  181
#define NLON  360
#define NPER  24
#define TP    192
#define NPT   3

typedef _Float16 f16;
typedef _Float16 f16x8 __attribute__((ext_vector_type(8)));
typedef _Float16 f16x4 __attribute__((ext_vector_type(4)));
typedef float    f32x4 __attribute__((ext_vector_type(4)));
typedef unsigned int u32;

#define ROWB      (NLON * 64)                       // bytes per (slot) row: 360*32*2
#define XT_BYTES  ((size_t)NB * 2 * NLAT * NLON * 32 * 2)  // 16,680,960 (256-aligned)
#define XS_BYTES  (3 * ROWB)                        // 69120 B LDS

// ---------------- prep: x transpose + weight transpose ----------------------
#define BROW 376
__global__ __launch_bounds__(256) void prep_kernel(
    const float* __restrict__ x, const float* __restrict__ weight,
    f16* __restrict__ xT, f16* __restrict__ wT)
{
    if (blockIdx.x == 4) {                    // weight slice: wT[k][f][c] = W[f][c][k]
        int wid = blockIdx.y * 2 + blockIdx.z;
        if (wid < 36) {
            int id = wid * 1024 + threadIdx.x * 4;
#pragma unroll
            for (int u = 0; u < 4; ++u) {
                int e = id + u;
                int c = e & 63, f = (e >> 6) & 63, k = e >> 12;
                wT[e] = (f16)weight[((size_t)(f * 64 + c)) * KS + k];
            }
        }
        return;
    }
    __shared__ f16 bounce[16 * BROW];
    const int tid = threadIdx.x;
    const int cq = blockIdx.x, lat = blockIdx.y, b = blockIdx.z;
    const float* xb = x + ((size_t)(b * CIN + cq * 16) * NLAT + lat) * NLON;
    for (int i = tid; i < 16 * 90; i += 256) {          // coalesced f32 -> f16 bounce
        int cl = i / 90, l4 = (i - cl * 90) * 4;
        float4 v = *(const float4*)(xb + (size_t)cl * (NLAT * NLON) + l4);
        f16x4 hh; hh[0] = (f16)v.x; hh[1] = (f16)v.y; hh[2] = (f16)v.z; hh[3] = (f16)v.w;
        *(f16x4*)&bounce[cl * BROW + l4] = hh;
    }
    __syncthreads();
    for (int j = tid; j < 720; j += 256) {              // transpose + swizzle, 16B stores
        int lon = j >> 1, oo = j & 1;
        int g  = cq * 2 + oo;                           // global oct 0..7
        int h  = g >> 2, oh = g & 3;
        int op = oh ^ ((lon >> 1) & 3);                 // baked bank swizzle
        f16x8 v;
#pragma unroll
        for (int jj = 0; jj < 8; ++jj) v[jj] = bounce[(oo * 8 + jj) * BROW + lon];
        *(f16x8*)&xT[((size_t)((b * 2 + h) * NLAT + lat) * NLON + lon) * 32 + op * 8] = v;
    }
}

// ---------------- main ------------------------------------------------------
__global__ __launch_bounds__(256, 2) void disco_main(
    const f16* __restrict__ xT, const f16* __restrict__ wT,
    const float* __restrict__ psi_vals,
    const int* __restrict__ psi_lat_in, const int* __restrict__ psi_lon_in,
    const float* __restrict__ bias, float* __restrict__ out)
{
    extern __shared__ f16 xs[];                 // [slot 3][lon 360][32c swizzled]
    const int tid  = threadIdx.x;
    const int lane = tid & 63, wave = tid >> 6;
    const int pn   = lane & 15, q = lane >> 4;
    const int pchunk = blockIdx.x, lat = blockIdx.y, b = blockIdx.z;
    const int pw = pchunk * TP + wave * 48;
    const int qs = q << 4;

    int r[3];
    r[0] = lat > 0 ? lat - 1 : 0;
    r[1] = lat;
    r[2] = lat < NLAT - 1 ? lat + 1 : NLAT - 1;

    int pl[NPT];
#pragma unroll
    for (int pt = 0; pt < NPT; ++pt) {
        int p = pw + pt * 16 + pn;
        pl[pt] = p >= NLON ? p - NLON : p;
    }

    f32x4 D[4][NPT];
#pragma unroll
    for (int ft = 0; ft < 4; ++ft)
#pragma unroll
        for (int pt = 0; pt < NPT; ++pt) D[ft][pt] = (f32x4){0.f, 0.f, 0.f, 0.f};

    for (int h = 0; h < 2; ++h) {
        __syncthreads();                        // previous-half readers done
        // stage 3 rows: pure linear copy (swizzle pre-baked in xT)
#pragma unroll
        for (int s = 0; s < 3; ++s) {
            const f16* src = xT + ((size_t)((b * 2 + h) * NLAT + r[s]) * NLON) * 32;
            f16* dst = xs + s * NLON * 32;
            for (int i = tid; i < 1440; i += 256)
                *(f16x8*)&dst[i * 8] = *(const f16x8*)&src[i * 8];
        }
        __syncthreads();

        for (int k = 0; k < KS; ++k) {
            f16x8 acc[NPT];
#pragma unroll
            for (int pt = 0; pt < NPT; ++pt)
                acc[pt] = (f16x8){0, 0, 0, 0, 0, 0, 0, 0};

            const int e0 = (k * NLAT + lat) * NPER;
#pragma unroll 4
            for (int t = 0; t < NPER; ++t) {
                const float pv  = psi_vals[e0 + t];          // wave-uniform -> s_load
                const int   li  = psi_lat_in[e0 + t];
                const int   lo64 = psi_lon_in[e0 + t] << 6;  // lon_in * 64 B
                const int   sb  = (li - lat + 1) * ROWB;     // slot byte base
                const f16 pvh = (f16)pv;
                const f16x8 pv8 = {pvh, pvh, pvh, pvh, pvh, pvh, pvh, pvh};
#pragma unroll
                for (int pt = 0; pt < NPT; ++pt) {
                    u32 a  = (u32)(lo64 + (pl[pt] << 6));
                    u32 aw = a - (u32)ROWB;                  // unsigned-wrap min trick
                    a = aw < a ? aw : a;
                    u32 addr = (u32)sb + a + (u32)(qs ^ ((a >> 3) & 48));
                    f16x8 xv = *(const f16x8*)((const char*)xs + addr);
                    acc[pt] += xv * pv8;                     // 4x v_pk_fma_f16
                }
            }
            // A fragments: wT[k][f][c], c = h*32 + q*8 + j, f = ft*16 + pn
            f16x8 Af[4];
            const f16* wk = wT + (size_t)k * 64 * 64 + h * 32 + q * 8;
#pragma unroll
            for (int ft = 0; ft < 4; ++ft)
                Af[ft] = *(const f16x8*)&wk[(ft * 16 + pn) * 64];
#pragma unroll
            for (int ft = 0; ft < 4; ++ft)
#pragma unroll
                for (int pt = 0; pt < NPT; ++pt)
                    D[ft][pt] = __builtin_amdgcn_mfma_f32_16x16x32_f16(
                        Af[ft], acc[pt], D[ft][pt], 0, 0, 0);
        }
    }

    // epilogue: D[m=f][n=p], lane: col = pn, rows (lane>>4)*4 + rr
#pragma unroll
    for (int ft = 0; ft < 4; ++ft) {
#pragma unroll
        for (int pt = 0; pt < NPT; ++pt) {
            const int p = pw + pt * 16 + pn;
            if (p < NLON) {
#pragma unroll
                for (int rr = 0; rr < 4; ++rr) {
                    const int f = ft * 16 + q * 4 + rr;
                    out[((size_t)(b * COUT + f) * NLAT + lat) * NLON + p] =
                        D[ft][pt][rr] + bias[f];
                }
            }
        }
    }
}

extern "C" void kernel_launch(void* const* d_in, const int* in_sizes, int n_in,
                              void* d_out, int out_size, void* d_ws, size_t ws_size,
                              hipStream_t stream) {
    const float* x          = (const float*)d_in[0];
    const float* psi_vals   = (const float*)d_in[1];
    const float* weight     = (const float*)d_in[2];
    const float* bias       = (const float*)d_in[3];
    const int*   psi_lat_in = (const int*)d_in[6];
    const int*   psi_lon_in = (const int*)d_in[7];
    float* out = (float*)d_out;

    f16* xT = (f16*)d_ws;                               // 16,680,960 B
    f16* wT = (f16*)((char*)d_ws + XT_BYTES);           // 73,728 B

    (void)hipFuncSetAttribute((const void*)disco_main,
                              hipFuncAttributeMaxDynamicSharedMemorySize, XS_BYTES);

    prep_kernel<<<dim3(5, NLAT, NB), 256, 0, stream>>>(x, weight, xT, wT);
    disco_main<<<dim3(2, NLAT, NB), 256, XS_BYTES, stream>>>(
        xT, wT, psi_vals, psi_lat_in, psi_lon_in, bias, out);
}

// Round 3
// 256.823 us; speedup vs baseline: 2.0570x; 1.1356x over previous
//
#include <hip/hip_runtime.h>

// DISCO S2 conv, round 3.
// prep (LDS-free): x -> xT f16 [b][h(c/32)][lat][lon][32c, oct^((lon>>1)&3) swizzled],
//                  weight -> wT f16 [k][f][c], taps -> meta int4 {pv_pk_f16x2, slot*ROWB, lon*64}.
// main: per (pchunk,lat,b) loop c-halves; linear-copy 3 swizzled rows to 69KB LDS (2 wg/CU);
//       gather taps in groups of 4 (12 independent ds_read_b128 in flight) with pk_fma f16
//       accumulating straight into MFMA B-fragments; 16x16x32_f16 MFMA; fused bias+store.

#define NB    2
#define CIN   64
#define COUT  64
#define KS    9
#define NLAT  181
#define NLON  360
#define NPER  24
#define TP    192
#define NPT   3

typedef _Float16 f16;
typedef _Float16 f16x8 __attribute__((ext_vector_type(8)));
typedef float    f32x4 __attribute__((ext_vector_type(4)));
typedef unsigned int u32;
typedef unsigned short u16;
typedef u32 u32x4 __attribute__((ext_vector_type(4)));

#define ROWB      23040                                   // 360*32*2 B per slot row
#define XT_BYTES  ((size_t)NB * 2 * NLAT * NLON * 32 * 2) // 16,680,960
#define WT_BYTES  (KS * 64 * 64 * 2)                      // 73,728
#define NMETA     (KS * NLAT * NPER)                      // 39,096
#define XS_BYTES  (3 * ROWB)                              // 69,120 B LDS

// ---------------- prep: all LDS-free --------------------------------------
__global__ __launch_bounds__(384) void prep_kernel(
    const float* __restrict__ x, const float* __restrict__ weight,
    const float* __restrict__ psi_vals, const int* __restrict__ psi_lat_in,
    const int* __restrict__ psi_lon_in,
    f16* __restrict__ xT, f16* __restrict__ wT, int4* __restrict__ meta)
{
    const int tid = threadIdx.x;
    const int bx = blockIdx.x, b = blockIdx.y;
    if (bx >= NLAT) {
        if (b != 0) return;
        if (bx == NLAT) {                     // wT[k][f][c] = W[f][c][k]
            for (int e = tid; e < KS * 64 * 64; e += 384) {
                int c = e & 63, f = (e >> 6) & 63, k = e >> 12;
                wT[e] = (f16)weight[((size_t)(f * 64 + c)) * KS + k];
            }
        } else {                              // packed tap metadata
            for (int e = tid; e < NMETA; e += 384) {
                int lat = (e / NPER) % NLAT;
                f16 pvh = (f16)psi_vals[e];
                u32 pb = (u32)__builtin_bit_cast(u16, pvh);
                int4 m;
                m.x = (int)((pb << 16) | pb);
                m.y = (psi_lat_in[e] - lat + 1) * ROWB;   // slot byte base, 0..2*ROWB
                m.z = psi_lon_in[e] << 6;                 // lon_in * 64 B
                m.w = 0;
                meta[e] = m;
            }
        }
        return;
    }
    // x transpose: per (lat,b); lanes = lon -> every channel-row read coalesced
    if (tid >= NLON) return;
    const int lat = bx, lon = tid;
    const int sw = (lon >> 1) & 3;
    for (int g = 0; g < 8; ++g) {             // oct = 8 channels
        const int h = g >> 2, oh = g & 3;
        const float* src = x + ((size_t)(b * CIN + g * 8) * NLAT + lat) * NLON + lon;
        f16x8 v;
#pragma unroll
        for (int j = 0; j < 8; ++j)
            v[j] = (f16)src[(size_t)j * NLAT * NLON];
        const int op = oh ^ sw;               // baked bank swizzle
        *(f16x8*)&xT[(((size_t)(b * 2 + h) * NLAT + lat) * NLON + lon) * 32 + op * 8] = v;
    }
}

// ---------------- main ------------------------------------------------------
__global__ __launch_bounds__(256, 2) void disco_main(
    const f16* __restrict__ xT, const f16* __restrict__ wT,
    const int4* __restrict__ meta, const float* __restrict__ bias,
    float* __restrict__ out)
{
    extern __shared__ char xs[];              // [slot 3][lon 360][32c swizzled] bytes
    const int tid  = threadIdx.x;
    const int lane = tid & 63, wave = tid >> 6;
    const int pn   = lane & 15, q = lane >> 4;
    const int pchunk = blockIdx.x, lat = blockIdx.y, b = blockIdx.z;
    const int pw = pchunk * TP + wave * 48;
    const u32 qs = (u32)(q << 4);

    int rr[3];
    rr[0] = lat > 0 ? lat - 1 : 0;
    rr[1] = lat;
    rr[2] = lat < NLAT - 1 ? lat + 1 : NLAT - 1;

    u32 pl64[NPT];
#pragma unroll
    for (int pt = 0; pt < NPT; ++pt) {
        int p = pw + pt * 16 + pn;
        if (p >= NLON) p -= NLON;
        pl64[pt] = (u32)(p << 6);
    }

    f32x4 D[4][NPT];
#pragma unroll
    for (int ft = 0; ft < 4; ++ft)
#pragma unroll
        for (int pt = 0; pt < NPT; ++pt) D[ft][pt] = (f32x4){0.f, 0.f, 0.f, 0.f};

    for (int h = 0; h < 2; ++h) {
        __syncthreads();                      // previous-half readers done
#pragma unroll
        for (int s = 0; s < 3; ++s) {         // linear copy (swizzle pre-baked)
            const f16* src = xT + (((size_t)(b * 2 + h) * NLAT + rr[s]) * NLON) * 32;
            f16* dst = (f16*)(xs + s * ROWB);
            for (int i = tid; i < 1440; i += 256)
                *(f16x8*)&dst[i * 8] = *(const f16x8*)&src[i * 8];
        }
        __syncthreads();

        for (int k = 0; k < KS; ++k) {
            f16x8 acc[NPT];
#pragma unroll
            for (int pt = 0; pt < NPT; ++pt) acc[pt] = (f16x8){0, 0, 0, 0, 0, 0, 0, 0};

            const int4* mp = meta + (k * NLAT + lat) * NPER;
            for (int tg = 0; tg < NPER; tg += 4) {
                int4 m[4];
#pragma unroll
                for (int j = 0; j < 4; ++j) m[j] = mp[tg + j];   // uniform -> s_load

                f16x8 xv[4][NPT];                                // 12 loads in flight
#pragma unroll
                for (int j = 0; j < 4; ++j) {
#pragma unroll
                    for (int pt = 0; pt < NPT; ++pt) {
                        u32 a  = (u32)m[j].z + pl64[pt];
                        u32 aw = a - (u32)ROWB;                  // unsigned wrap-min
                        a = aw < a ? aw : a;
                        u32 addr = a + (qs ^ ((a >> 3) & 48u)) + (u32)m[j].y;
                        xv[j][pt] = *(const f16x8*)(xs + addr);
                    }
                }
#pragma unroll
                for (int j = 0; j < 4; ++j) {
                    u32x4 pkv = {(u32)m[j].x, (u32)m[j].x, (u32)m[j].x, (u32)m[j].x};
                    f16x8 pv8 = __builtin_bit_cast(f16x8, pkv);
#pragma unroll
                    for (int pt = 0; pt < NPT; ++pt)
                        acc[pt] += xv[j][pt] * pv8;              // v_pk_fma_f16
                }
            }

            // A fragments: wT[k][f][c], c = h*32 + q*8 + j, f = ft*16 + pn
            f16x8 Af[4];
            const f16* wk = wT + (size_t)k * 64 * 64 + h * 32 + q * 8;
#pragma unroll
            for (int ft = 0; ft < 4; ++ft)
                Af[ft] = *(const f16x8*)&wk[(ft * 16 + pn) * 64];
#pragma unroll
            for (int ft = 0; ft < 4; ++ft)
#pragma unroll
                for (int pt = 0; pt < NPT; ++pt)
                    D[ft][pt] = __builtin_amdgcn_mfma_f32_16x16x32_f16(
                        Af[ft], acc[pt], D[ft][pt], 0, 0, 0);
        }
    }

    // epilogue: D[m=f][n=p], lane: col = pn, rows (lane>>4)*4 + rr
#pragma unroll
    for (int ft = 0; ft < 4; ++ft) {
#pragma unroll
        for (int pt = 0; pt < NPT; ++pt) {
            const int p = pw + pt * 16 + pn;
            if (p < NLON) {
#pragma unroll
                for (int r = 0; r < 4; ++r) {
                    const int f = ft * 16 + q * 4 + r;
                    out[((size_t)(b * COUT + f) * NLAT + lat) * NLON + p] =
                        D[ft][pt][r] + bias[f];
                }
            }
        }
    }
}

extern "C" void kernel_launch(void* const* d_in, const int* in_sizes, int n_in,
                              void* d_out, int out_size, void* d_ws, size_t ws_size,
                              hipStream_t stream) {
    const float* x          = (const float*)d_in[0];
    const float* psi_vals   = (const float*)d_in[1];
    const float* weight     = (const float*)d_in[2];
    const float* bias       = (const float*)d_in[3];
    const int*   psi_lat_in = (const int*)d_in[6];
    const int*   psi_lon_in = (const int*)d_in[7];
    float* out = (float*)d_out;

    f16*  xT   = (f16*)d_ws;
    f16*  wT   = (f16*)((char*)d_ws + XT_BYTES);
    int4* meta = (int4*)((char*)d_ws + XT_BYTES + WT_BYTES);

    (void)hipFuncSetAttribute((const void*)disco_main,
                              hipFuncAttributeMaxDynamicSharedMemorySize, XS_BYTES);

    prep_kernel<<<dim3(NLAT + 2, NB), 384, 0, stream>>>(
        x, weight, psi_vals, psi_lat_in, psi_lon_in, xT, wT, meta);
    disco_main<<<dim3(2, NLAT, NB), 256, XS_BYTES, stream>>>(
        xT, wT, meta, bias, out);
}

// Round 4
// 216.686 us; speedup vs baseline: 2.4381x; 1.1852x over previous
//
#include <hip/hip_runtime.h>

// DISCO S2 conv, round 4.
// prep: x -> xT f16 [b][h][lat][lon][32c, oct^((lon>>1)&3) swizzled] (grid 181x2x8, LDS-free),
//       weight -> wT f16 [k][f][c], taps -> meta int4 {psi_pk, slot*ROWB+lon*64, lon*64, 0}.
// main: 512-thread wgs (8 waves x one 16-p tile, TP=128) -> 16 waves/CU = 4/SIMD at 69KB LDS.
//       Per c-half: linear-stage 3 rows; per k: 24 taps in groups of 8 (s_load_dwordx16 meta,
//       8 ds_read_b128 in flight, 6-VALU addressing, pk_fma f16 into B-frag), 4x mfma 16x16x32_f16.

#define NB    2
#define CIN   64
#define COUT  64
#define KS    9
#define NLAT  181
#define NLON  360
#define NPER  24
#define TP    128

typedef _Float16 f16;
typedef _Float16 f16x8 __attribute__((ext_vector_type(8)));
typedef float    f32x4 __attribute__((ext_vector_type(4)));
typedef unsigned int u32;
typedef unsigned short u16;
typedef u32 u32x4 __attribute__((ext_vector_type(4)));

#define ROWB      23040                                   // 360*32*2 B per slot row (low 9 bits = 0)
#define XT_BYTES  ((size_t)NB * 2 * NLAT * NLON * 32 * 2) // 16,680,960
#define WT_BYTES  (KS * 64 * 64 * 2)                      // 73,728
#define NMETA     (KS * NLAT * NPER)                      // 39,096
#define XS_BYTES  (3 * ROWB)                              // 69,120 B LDS

// ---------------- prep ------------------------------------------------------
__global__ __launch_bounds__(384) void prep_kernel(
    const float* __restrict__ x, const float* __restrict__ weight,
    const float* __restrict__ psi_vals, const int* __restrict__ psi_lat_in,
    const int* __restrict__ psi_lon_in,
    f16* __restrict__ xT, f16* __restrict__ wT, int4* __restrict__ meta)
{
    const int tid = threadIdx.x;
    const int lat = blockIdx.x, b = blockIdx.y, z = blockIdx.z;
    if (z == 8) {                             // wT[k][f][c] = W[f][c][k], 36 blocks
        if (b == 0 && lat < 36 && tid < 256) {
            int e0 = lat * 1024 + tid * 4;
#pragma unroll
            for (int u = 0; u < 4; ++u) {
                int e = e0 + u;
                int c = e & 63, f = (e >> 6) & 63, k = e >> 12;
                wT[e] = (f16)weight[((size_t)(f * 64 + c)) * KS + k];
            }
        }
        return;
    }
    if (z == 9) {                             // packed tap metadata, 153 blocks
        if (b == 0 && lat < 153 && tid < 256) {
            int e = lat * 256 + tid;
            if (e < NMETA) {
                int lt = (e / NPER) % NLAT;
                f16 pvh = (f16)psi_vals[e];
                u32 pb = (u32)__builtin_bit_cast(u16, pvh);
                int lonb = psi_lon_in[e] << 6;
                int4 m;
                m.x = (int)((pb << 16) | pb);
                m.y = (psi_lat_in[e] - lt + 1) * ROWB + lonb;  // combined byte base
                m.z = lonb;                                    // for wrap compare
                m.w = 0;
                meta[e] = m;
            }
        }
        return;
    }
    // x transpose: one (lat, b, oct g=z) per block; lanes = lon -> coalesced
    if (tid >= NLON) return;
    const int g = z, lon = tid;
    const int h = g >> 2, oh = g & 3;
    const float* src = x + ((size_t)(b * CIN + g * 8) * NLAT + lat) * NLON + lon;
    f16x8 v;
#pragma unroll
    for (int j = 0; j < 8; ++j)
        v[j] = (f16)src[(size_t)j * NLAT * NLON];
    const int op = oh ^ ((lon >> 1) & 3);     // baked bank swizzle
    *(f16x8*)&xT[(((size_t)(b * 2 + h) * NLAT + lat) * NLON + lon) * 32 + op * 8] = v;
}

// ---------------- main ------------------------------------------------------
__global__ __launch_bounds__(512, 4) void disco_main(
    const f16* __restrict__ xT, const f16* __restrict__ wT,
    const int4* __restrict__ meta, const float* __restrict__ bias,
    float* __restrict__ out)
{
    extern __shared__ char xs[];              // [slot 3][lon 360][32c swizzled]
    const int tid  = threadIdx.x;
    const int lane = tid & 63, wave = tid >> 6;   // 8 waves
    const int pn   = lane & 15, q = lane >> 4;
    const int pchunk = blockIdx.x, lat = blockIdx.y, b = blockIdx.z;

    const int p  = pchunk * TP + wave * 16 + pn;  // 0..383 (>=360 masked at store)
    const int pl = p >= NLON ? p - NLON : p;
    const u32 plq  = (u32)((pl << 6) + (q << 4)); // p*64 + q*16 (bits 4,5 = q)
    const u32 plqm = plq - (u32)ROWB;             // wrapped variant
    const u32 thr  = (u32)((NLON - pl) << 6);     // wrap iff lon*64 >= thr

    int rr0 = lat > 0 ? lat - 1 : 0;
    int rr2 = lat < NLAT - 1 ? lat + 1 : NLAT - 1;

    f32x4 D[4];
#pragma unroll
    for (int ft = 0; ft < 4; ++ft) D[ft] = (f32x4){0.f, 0.f, 0.f, 0.f};

    for (int h = 0; h < 2; ++h) {
        __syncthreads();                      // previous-half readers done
        {
            const size_t hb = (size_t)(b * 2 + h) * NLAT;
            const f16* s0 = xT + (hb + rr0) * NLON * 32;
            const f16* s1 = xT + (hb + lat) * NLON * 32;
            const f16* s2 = xT + (hb + rr2) * NLON * 32;
            for (int i = tid; i < 1440; i += 512) {
                *(f16x8*)&xs[i * 16]             = *(const f16x8*)&s0[i * 8];
                *(f16x8*)&xs[ROWB + i * 16]      = *(const f16x8*)&s1[i * 8];
                *(f16x8*)&xs[2 * ROWB + i * 16]  = *(const f16x8*)&s2[i * 8];
            }
        }
        __syncthreads();

        for (int k = 0; k < KS; ++k) {
            f16x8 acc = (f16x8){0, 0, 0, 0, 0, 0, 0, 0};
            const int4* mp = meta + (k * NLAT + lat) * NPER;
#pragma unroll
            for (int tg = 0; tg < NPER; tg += 8) {
                int4 m[8];
#pragma unroll
                for (int j = 0; j < 8; ++j) m[j] = mp[tg + j];   // uniform -> s_load x16

                u32 addr[8];
#pragma unroll
                for (int j = 0; j < 8; ++j) {
                    u32 ad = ((u32)m[j].z >= thr) ? plqm : plq;  // cmp + cndmask
                    u32 a  = (u32)m[j].y + ad;
                    addr[j] = a ^ ((a >> 3) & 48u);              // bank swizzle
                }
                f16x8 xv[8];                                     // 8 b128 in flight
#pragma unroll
                for (int j = 0; j < 8; ++j)
                    xv[j] = *(const f16x8*)(xs + addr[j]);
#pragma unroll
                for (int j = 0; j < 8; ++j) {
                    u32 pk = (u32)m[j].x;
                    u32x4 pkv = {pk, pk, pk, pk};
                    acc += xv[j] * __builtin_bit_cast(f16x8, pkv); // v_pk_fma_f16
                }
            }

            // A frags: wT[k][f][c], c = h*32 + q*8 + j, f = ft*16 + pn
            f16x8 Af[4];
            const f16* wk = wT + (size_t)k * 4096 + h * 32 + q * 8;
#pragma unroll
            for (int ft = 0; ft < 4; ++ft)
                Af[ft] = *(const f16x8*)&wk[(ft * 16 + pn) * 64];
#pragma unroll
            for (int ft = 0; ft < 4; ++ft)
                D[ft] = __builtin_amdgcn_mfma_f32_16x16x32_f16(Af[ft], acc, D[ft], 0, 0, 0);
        }
    }

    // epilogue: D[m=f][n=p], lane: col = pn, rows (lane>>4)*4 + rr
    if (p < NLON) {
#pragma unroll
        for (int ft = 0; ft < 4; ++ft)
#pragma unroll
            for (int r = 0; r < 4; ++r) {
                const int f = ft * 16 + q * 4 + r;
                out[((size_t)(b * COUT + f) * NLAT + lat) * NLON + p] = D[ft][r] + bias[f];
            }
    }
}

extern "C" void kernel_launch(void* const* d_in, const int* in_sizes, int n_in,
                              void* d_out, int out_size, void* d_ws, size_t ws_size,
                              hipStream_t stream) {
    const float* x          = (const float*)d_in[0];
    const float* psi_vals   = (const float*)d_in[1];
    const float* weight     = (const float*)d_in[2];
    const float* bias       = (const float*)d_in[3];
    const int*   psi_lat_in = (const int*)d_in[6];
    const int*   psi_lon_in = (const int*)d_in[7];
    float* out = (float*)d_out;

    f16*  xT   = (f16*)d_ws;
    f16*  wT   = (f16*)((char*)d_ws + XT_BYTES);
    int4* meta = (int4*)((char*)d_ws + XT_BYTES + WT_BYTES);

    (void)hipFuncSetAttribute((const void*)disco_main,
                              hipFuncAttributeMaxDynamicSharedMemorySize, XS_BYTES);

    prep_kernel<<<dim3(NLAT, NB, 10), 384, 0, stream>>>(
        x, weight, psi_vals, psi_lat_in, psi_lon_in, xT, wT, meta);
    disco_main<<<dim3(3, NLAT, NB), 512, XS_BYTES, stream>>>(
        xT, wT, meta, bias, out);
}